// Round 1
// baseline (307.632 us; speedup 1.0000x reference)
//
#include <hip/hip_runtime.h>
#include <hip/hip_bf16.h>
#include <math.h>

// ---------------- types ----------------
typedef short s16x8 __attribute__((ext_vector_type(8)));
typedef float f32x4 __attribute__((ext_vector_type(4)));

// ---------------- fp32 -> bf16 (RNE) ----------------
__device__ inline unsigned short f2bf(float x) {
    unsigned int u = __float_as_uint(x);
    unsigned int r = (u + 0x7fffu + ((u >> 16) & 1u)) >> 16;
    return (unsigned short)r;
}

__global__ void cvt_kernel(const float* __restrict__ src,
                           unsigned short* __restrict__ dst, int n4) {
    int i = blockIdx.x * blockDim.x + threadIdx.x;
    if (i >= n4) return;
    float4 v = ((const float4*)src)[i];
    ushort4 o;
    o.x = f2bf(v.x); o.y = f2bf(v.y); o.z = f2bf(v.z); o.w = f2bf(v.w);
    ((ushort4*)dst)[i] = o;
}

// ---------------- GEMM: H = tanh(x @ W_ih^T + b_ih + b_hh) ----------------
// A: (8192, 2048) bf16 row-major (K contiguous)
// Bm: (2048, 2048) bf16 row-major = W_ih, rows are output cols (K contiguous)
// 128x128 tile, BK=32, 256 threads (4 waves, 2x2 of 64x64), 16x16x32 MFMA.
__global__ __launch_bounds__(256) void gemm_tanh_kernel(
    const unsigned short* __restrict__ A, const unsigned short* __restrict__ Bm,
    const float* __restrict__ b_ih, const float* __restrict__ b_hh,
    float* __restrict__ H)
{
    __shared__ unsigned short As[128 * 32];  // 8 KB
    __shared__ unsigned short Bs[128 * 32];  // 8 KB

    const int tid  = threadIdx.x;
    const int lane = tid & 63;
    const int wave = tid >> 6;
    const int row0 = blockIdx.y * 128;
    const int col0 = blockIdx.x * 128;
    const int wr = (wave >> 1) * 64;
    const int wc = (wave & 1) * 64;
    const int quad = lane >> 4;
    const int mrow = lane & 15;

    f32x4 acc[4][4];
#pragma unroll
    for (int i = 0; i < 4; ++i)
#pragma unroll
        for (int j = 0; j < 4; ++j)
            acc[i][j] = f32x4{0.f, 0.f, 0.f, 0.f};

    for (int k0 = 0; k0 < 2048; k0 += 32) {
        __syncthreads();  // previous iter's ds_reads done before overwrite
        // stage A tile: 128 rows x 32 bf16 = 8KB = 512 x 16B chunks; 2/thread
#pragma unroll
        for (int i = 0; i < 2; ++i) {
            int t = i * 256 + tid;
            int r = t >> 2, c = t & 3;
            const unsigned short* gp = A + (size_t)(row0 + r) * 2048 + k0 + c * 8;
            __builtin_amdgcn_global_load_lds(
                (const __attribute__((address_space(1))) void*)gp,
                (__attribute__((address_space(3))) void*)(&As[t * 8]), 16, 0, 0);
        }
#pragma unroll
        for (int i = 0; i < 2; ++i) {
            int t = i * 256 + tid;
            int r = t >> 2, c = t & 3;
            const unsigned short* gp = Bm + (size_t)(col0 + r) * 2048 + k0 + c * 8;
            __builtin_amdgcn_global_load_lds(
                (const __attribute__((address_space(1))) void*)gp,
                (__attribute__((address_space(3))) void*)(&Bs[t * 8]), 16, 0, 0);
        }
        __syncthreads();  // compiler emits vmcnt(0) drain before barrier

        s16x8 af[4], bfr[4];
#pragma unroll
        for (int i = 0; i < 4; ++i)
            af[i] = *(const s16x8*)(&As[(wr + i * 16 + mrow) * 32 + quad * 8]);
#pragma unroll
        for (int j = 0; j < 4; ++j)
            bfr[j] = *(const s16x8*)(&Bs[(wc + j * 16 + mrow) * 32 + quad * 8]);
#pragma unroll
        for (int i = 0; i < 4; ++i)
#pragma unroll
            for (int j = 0; j < 4; ++j)
                acc[i][j] = __builtin_amdgcn_mfma_f32_16x16x32_bf16(
                    af[i], bfr[j], acc[i][j], 0, 0, 0);
    }

    // epilogue: C/D layout col=lane&15, row=quad*4+reg
#pragma unroll
    for (int i = 0; i < 4; ++i) {
#pragma unroll
        for (int r = 0; r < 4; ++r) {
            int grow = row0 + wr + i * 16 + quad * 4 + r;
#pragma unroll
            for (int j = 0; j < 4; ++j) {
                int gc = col0 + wc + j * 16 + mrow;
                float v = acc[i][j][r] + b_ih[gc] + b_hh[gc];
                H[(size_t)grow * 2048 + gc] = tanhf(v);
            }
        }
    }
}

// ---------------- AvgPool1d(k=45, s=45) over hidden dim ----------------
// pooled_t: (45, 8192) feature-major so the scan reads contiguously
__global__ void pool_kernel(const float* __restrict__ H,
                            float* __restrict__ pooled_t) {
    __shared__ float sh[2025];
    int b = blockIdx.x;
    int tid = threadIdx.x;
    const float* hp = H + (size_t)b * 2048;
    for (int i = tid; i < 2025; i += 256) sh[i] = hp[i];
    __syncthreads();
    if (tid < 45) {
        float s = 0.f;
#pragma unroll
        for (int k = 0; k < 45; ++k) s += sh[tid * 45 + k];
        pooled_t[tid * 8192 + b] = s * (1.0f / 45.0f);
    }
}

// ---------------- per-feature prefix sums of pooled and pooled^2 ----------------
// one block per feature; 256 threads x 32 sequential elems + block scan
__global__ void scan_kernel(const float* __restrict__ pooled_t,
                            float* __restrict__ cs_t, float* __restrict__ cs2_t) {
    __shared__ float sh[8192];
    __shared__ float t1[256], t2[256];
    int f = blockIdx.x;
    int tid = threadIdx.x;
    const float* p = pooled_t + f * 8192;
    for (int i = tid; i < 8192; i += 256) sh[i] = p[i];
    __syncthreads();
    int base = tid * 32;
    float s1 = 0.f, s2 = 0.f;
#pragma unroll
    for (int i = 0; i < 32; ++i) { float v = sh[base + i]; s1 += v; s2 += v * v; }
    t1[tid] = s1; t2[tid] = s2;
    __syncthreads();
    for (int d = 1; d < 256; d <<= 1) {
        float a1 = (tid >= d) ? t1[tid - d] : 0.f;
        float a2 = (tid >= d) ? t2[tid - d] : 0.f;
        __syncthreads();
        t1[tid] += a1; t2[tid] += a2;
        __syncthreads();
    }
    float r1 = t1[tid] - s1, r2 = t2[tid] - s2;  // exclusive offsets
    float* c1 = cs_t + f * 8192;
    float* c2 = cs2_t + f * 8192;
#pragma unroll
    for (int i = 0; i < 32; ++i) {
        float v = sh[base + i];
        r1 += v; r2 += v * v;
        c1[base + i] = r1; c2[base + i] = r2;
    }
}

// ---------------- windowed mean/var -> est (B, 270) ----------------
__global__ void est_kernel(const float* __restrict__ cs_t,
                           const float* __restrict__ cs2_t,
                           float* __restrict__ est) {
    int b = blockIdx.x * 256 + threadIdx.x;
    int fj = blockIdx.y;              // 0..134
    int f = fj / 3, j = fj % 3;
    int L = (j == 0) ? 32 : (j == 1) ? 128 : 512;
    const float* c1 = cs_t + f * 8192;
    const float* c2 = cs2_t + f * 8192;
    float a1 = c1[b], a2 = c2[b];
    float p1 = 0.f, p2 = 0.f;
    if (b >= L) { p1 = c1[b - L]; p2 = c2[b - L]; }
    float cnt = (float)((b + 1 < L) ? (b + 1) : L);
    float m = (a1 - p1) / cnt;
    float v = (a2 - p2) / cnt - m * m;
    float* e = est + (size_t)b * 270 + f * 6 + j * 2;
    e[0] = m; e[1] = v;
}

// ---------------- logits = [H, est] @ W_lin^T + b_lin, softmax ----------------
// one wave per 4 rows; lanes stride K=2318; butterfly reduce; lanes 0..3 softmax
__global__ __launch_bounds__(256) void final_kernel(
    const float* __restrict__ H, const float* __restrict__ est,
    const float* __restrict__ W_lin, const float* __restrict__ b_lin,
    float* __restrict__ out) {
    int tid = threadIdx.x;
    int lane = tid & 63;
    int wave = tid >> 6;
    int row_base = blockIdx.x * 16 + wave * 4;
    float acc[4][10];
#pragma unroll
    for (int r = 0; r < 4; ++r)
#pragma unroll
        for (int c = 0; c < 10; ++c) acc[r][c] = 0.f;

    for (int idx = lane; idx < 2318; idx += 64) {
        float wv[10];
#pragma unroll
        for (int c = 0; c < 10; ++c) wv[c] = W_lin[c * 2318 + idx];
#pragma unroll
        for (int r = 0; r < 4; ++r) {
            int row = row_base + r;
            float v = (idx < 2048) ? H[(size_t)row * 2048 + idx]
                                   : est[(size_t)row * 270 + (idx - 2048)];
#pragma unroll
            for (int c = 0; c < 10; ++c) acc[r][c] += v * wv[c];
        }
    }
#pragma unroll
    for (int d = 1; d < 64; d <<= 1)
#pragma unroll
        for (int r = 0; r < 4; ++r)
#pragma unroll
            for (int c = 0; c < 10; ++c)
                acc[r][c] += __shfl_xor(acc[r][c], d);

    if (lane < 4) {
        int r = lane;
        int row = row_base + r;
        float lg[10];
        float mx = -1e30f;
#pragma unroll
        for (int c = 0; c < 10; ++c) {
            lg[c] = acc[r][c] + b_lin[c];
            mx = fmaxf(mx, lg[c]);
        }
        float s = 0.f;
#pragma unroll
        for (int c = 0; c < 10; ++c) { lg[c] = expf(lg[c] - mx); s += lg[c]; }
        float inv = 1.0f / s;
#pragma unroll
        for (int c = 0; c < 10; ++c) out[(size_t)row * 10 + c] = lg[c] * inv;
    }
}

// ---------------- launch ----------------
extern "C" void kernel_launch(void* const* d_in, const int* in_sizes, int n_in,
                              void* d_out, int out_size, void* d_ws, size_t ws_size,
                              hipStream_t stream) {
    const float* x     = (const float*)d_in[0];   // (8192,1,2048)
    const float* W_ih  = (const float*)d_in[1];   // (2048,2048)
    // d_in[2] = W_hh unused: h0 == 0 so the recurrent term vanishes
    const float* b_ih  = (const float*)d_in[3];
    const float* b_hh  = (const float*)d_in[4];
    const float* W_lin = (const float*)d_in[5];   // (10, 2318)
    const float* b_lin = (const float*)d_in[6];
    float* out = (float*)d_out;

    char* ws = (char*)d_ws;
    unsigned short* xb = (unsigned short*)(ws);                 // 33554432 B
    unsigned short* wb = (unsigned short*)(ws + 33554432);      //  8388608 B
    float* H        = (float*)(ws + 41943040);                  // 67108864 B
    float* pooled_t = (float*)(ws + 109051904);                 //  1474560 B
    float* cs_t     = (float*)(ws + 110526464);                 //  1474560 B
    float* cs2_t    = (float*)(ws + 112001024);                 //  1474560 B
    float* est      = (float*)(ws + 113475584);                 //  8847360 B (tot ~117 MB)

    cvt_kernel<<<16384, 256, 0, stream>>>(x, xb, 4194304);
    cvt_kernel<<<4096, 256, 0, stream>>>(W_ih, wb, 1048576);
    dim3 ggrid(16, 64);
    gemm_tanh_kernel<<<ggrid, 256, 0, stream>>>(xb, wb, b_ih, b_hh, H);
    pool_kernel<<<8192, 256, 0, stream>>>(H, pooled_t);
    scan_kernel<<<45, 256, 0, stream>>>(pooled_t, cs_t, cs2_t);
    dim3 egrid(32, 135);
    est_kernel<<<egrid, 256, 0, stream>>>(cs_t, cs2_t, est);
    final_kernel<<<512, 256, 0, stream>>>(H, est, W_lin, b_lin, out);
}